// Round 15
// baseline (103.264 us; speedup 1.0000x reference)
//
#include <hip/hip_runtime.h>
#include <hip/hip_bf16.h>

// Problem: B=4096, IN=1024, H=1024.
// pre = x@U^T + h@W^T + Ub -> gates -> h_t, c_t   (fused after convert)
// GEMM: M=4096 (batch), N=4096 (4H permuted), K=2048 (IN+H concat)
//
// Round-15: r14 (= r9 best, 82.0 us) with the MFMA shape switched to
// 32x32x16 (µbench 2382 vs 2075 TF, half the instruction count).
// Same LDS layout/swizzle/staging/phase skeleton as r14.
//  - reader: row = base + (lane&31); k-slot = ks*2 + (lane>>5);
//    cell = kslot ^ (((lane&31)>>1)&7)  [conflict-free: 2 lanes/cell per
//    16-lane phase group, same family as r14's measured-zero pattern]
//  - acc[4][2] of f32x16; phase (mh,kk) = 8 MFMA (2m x 2n x 2ks).
//  - C/D layout (verified): col=lane&31, row=(reg&3)+8*(reg>>2)+4*(lane>>5).
//    Gate parity = lane bit4: frag n holds gates {2n,2n+1} split at lane^16;
//    one shfl_xor(16) pair per element reunites 4 gates at one (row,j);
//    lo lane writes h_t, hi lane writes c_t.

#define BATCH 4096
#define HID   1024
#define KDIM  2048

#define BM 256
#define BN 256
#define BK 64
#define NITER (KDIM / (2 * BK))   // 16

typedef __bf16 bf16x8 __attribute__((ext_vector_type(8)));
typedef float  f32x16 __attribute__((ext_vector_type(16)));

__device__ __forceinline__ void async_load16(const void* g, void* l) {
    __builtin_amdgcn_global_load_lds(
        (const __attribute__((address_space(1))) void*)g,
        (__attribute__((address_space(3))) void*)l,
        16, 0, 0);
}

__device__ __forceinline__ float sigmoidf_(float v) {
    return 1.0f / (1.0f + __expf(-v));
}
__device__ __forceinline__ float tanhf_(float v) {
    return 1.0f - 2.0f / (__expf(2.0f * v) + 1.0f);
}

// ---------------------------------------------------------------------------
// Kernel 1: f32 -> bf16 conversion + K-concat; B side gate-permuted.
// ---------------------------------------------------------------------------
__global__ __launch_bounds__(256) void convert_kernel(
    const float* __restrict__ x, const float* __restrict__ h,
    const float* __restrict__ U, const float* __restrict__ W,
    __hip_bfloat16* __restrict__ Acat, __hip_bfloat16* __restrict__ Bcat)
{
    const int CH_PER_MAT = (4096 * KDIM) / 8;
    int idx = blockIdx.x * blockDim.x + threadIdx.x;
    bool isB = idx >= CH_PER_MAT;
    int c = isB ? (idx - CH_PER_MAT) : idx;
    int row  = c >> 8;
    int col  = (c & 255) << 3;
    int srow = row;
    if (isB) {
        int g  = (row >> 4) & 3;
        int j  = ((row >> 8) << 6) + (((row >> 6) & 3) << 4) + (row & 15);
        srow = g * 1024 + j;
    }
    const float* src;
    if (col < 1024) src = (isB ? U : x) + (size_t)srow * 1024 + col;
    else            src = (isB ? W : h) + (size_t)srow * 1024 + (col - 1024);
    float4 v0 = *(const float4*)(src);
    float4 v1 = *(const float4*)(src + 4);
    __hip_bfloat16 tmp[8];
    tmp[0] = __float2bfloat16(v0.x); tmp[1] = __float2bfloat16(v0.y);
    tmp[2] = __float2bfloat16(v0.z); tmp[3] = __float2bfloat16(v0.w);
    tmp[4] = __float2bfloat16(v1.x); tmp[5] = __float2bfloat16(v1.y);
    tmp[6] = __float2bfloat16(v1.z); tmp[7] = __float2bfloat16(v1.w);
    __hip_bfloat16* dst = (isB ? Bcat : Acat) + (size_t)row * KDIM + col;
    *(bf16x8*)dst = *(const bf16x8*)tmp;
}

// ---------------------------------------------------------------------------
// Kernel 2: fused bf16 GEMM + LSTM gates, 8-phase schedule, 32x32x16 MFMA.
// ---------------------------------------------------------------------------
__global__ __launch_bounds__(512, 1) void gemm_lstm_kernel(
    const __hip_bfloat16* __restrict__ A,   // [4096][2048]
    const __hip_bfloat16* __restrict__ Bm,  // [4096][2048] gate-permuted
    const float* __restrict__ Ub,           // [4096]
    const float* __restrict__ c_prev,       // [4096][1024]
    float* __restrict__ out)                // h_t ++ c_t
{
    __shared__ __align__(16) unsigned char smem[131072];  // 2 bufs x 64 KB

    const int tid  = threadIdx.x;
    const int lane = tid & 63;
    const int wid  = tid >> 6;
    const int wm   = wid >> 2;     // 0..1
    const int wn   = wid & 3;      // 0..3

    // L2-locality map (r7): each XCD owns a 4x8 rectangle of the 16x16 grid.
    int wg  = blockIdx.x;
    const int xcd = wg & 7;
    const int i_  = wg >> 3;
    const int bm = ((xcd >> 1) << 2) + (i_ >> 3);
    const int bn = ((xcd & 1) << 3) + (i_ & 7);

    const __hip_bfloat16* Ab = A  + (size_t)bm * BM * KDIM;
    const __hip_bfloat16* Bb = Bm + (size_t)bn * BN * KDIM;

    // ds_read addressing (32x32 fragments):
    // row = base + l31, kslot = ks*2 + lhi, cell = kslot ^ ((l31>>1)&7).
    const int l31 = lane & 31;
    const int lhi = lane >> 5;                          // 0/1
    const int e7  = (l31 >> 1) & 7;
    const unsigned lrow = (unsigned)l31 * 128u;
    const unsigned cs0 = (unsigned)(((0 * 2 + lhi) ^ e7) << 4);
    const unsigned cs1 = (unsigned)(((0 * 2 + 1 - lhi + lhi * 2) ^ e7) << 4); // (1+lhi)... see below
    // simpler: compute all four explicitly
    const unsigned csA = (unsigned)(((0 + lhi) ^ e7) << 4);   // ks0 slot
    const unsigned csB = (unsigned)(((2 + lhi) ^ e7) << 4);   // ks1 slot
    const unsigned csC = (unsigned)(((4 + lhi) ^ e7) << 4);   // ks2 slot
    const unsigned csD = (unsigned)(((6 + lhi) ^ e7) << 4);   // ks3 slot
    (void)cs0; (void)cs1;
    const unsigned wmBase = (unsigned)wm * 16384u;            // A half
    const unsigned bnBase = (unsigned)(wn >> 1) * 16384u;     // B 128-row half
    const unsigned bnRowB = (unsigned)(wn & 1) * 8192u;       // 64-row quarter

    // staging (identical to r14): linear LDS dest, pre-swizzled source.
    const int ch0 = tid,           ch1 = 512 + tid;
    const int sr0 = ch0 >> 3,      sr1 = ch1 >> 3;
    const int sc0 = ((ch0 & 7) ^ ((sr0 >> 1) & 7)) << 3;
    const int sc1 = ((ch1 & 7) ^ ((sr1 >> 1) & 7)) << 3;
    const size_t ga0 = (size_t)sr0 * KDIM + sc0;
    const size_t ga1 = (size_t)sr1 * KDIM + sc1;

    f32x16 acc[4][2] = {};
    // E/O ping-pong fragment sets: [0]=m0/ks_lo [1]=m0/ks_hi [2]=m1/ks_lo [3]=m1/ks_hi
    bf16x8 aE[4], aO[4], bE[4], bO[4];

#define RD16(B) (*(const bf16x8*)(smem + (B)))
// A quad for (buf, mh, kk): m in {0,1} (32-row frags), ks in {kk*2, kk*2+1}
#define LDA4(SET, BUFB, MH, KSL, KSH) do { \
    const unsigned _b = (BUFB) + wmBase + (unsigned)(MH) * 8192u + lrow; \
    SET[0] = RD16(_b +          (KSL)); \
    SET[1] = RD16(_b +          (KSH)); \
    SET[2] = RD16(_b + 4096u +  (KSL)); \
    SET[3] = RD16(_b + 4096u +  (KSH)); } while (0)
// B quad for (buf, kk): n in {0,1}
#define LDB4(SET, BUFB, KSL, KSH) do { \
    const unsigned _b = (BUFB) + 32768u + bnBase + bnRowB + lrow; \
    SET[0] = RD16(_b +          (KSL)); \
    SET[1] = RD16(_b +          (KSH)); \
    SET[2] = RD16(_b + 4096u +  (KSL)); \
    SET[3] = RD16(_b + 4096u +  (KSH)); } while (0)
#define STG_A(TSRC, BUFB, H) do { \
    const unsigned _rg = (BUFB) + (H)*16384u; \
    const __hip_bfloat16* _s = Ab + (size_t)(H)*128*KDIM + (size_t)(TSRC)*64; \
    async_load16(_s + ga0, smem + _rg + (unsigned)ch0*16u); \
    async_load16(_s + ga1, smem + _rg + (unsigned)ch1*16u); } while (0)
#define STG_B(TSRC, BUFB, H) do { \
    const unsigned _rg = (BUFB) + 32768u + (H)*16384u; \
    const __hip_bfloat16* _s = Bb + (size_t)(H)*128*KDIM + (size_t)(TSRC)*64; \
    async_load16(_s + ga0, smem + _rg + (unsigned)ch0*16u); \
    async_load16(_s + ga1, smem + _rg + (unsigned)ch1*16u); } while (0)
// 8 MFMA: (m,n,ks) over 2x2x2; MB = mh*2
#define MF8(ASET, BSET, MB) do { \
    __builtin_amdgcn_s_setprio(1); \
    acc[(MB)+0][0] = __builtin_amdgcn_mfma_f32_32x32x16_bf16(ASET[0], BSET[0], acc[(MB)+0][0], 0, 0, 0); \
    acc[(MB)+0][1] = __builtin_amdgcn_mfma_f32_32x32x16_bf16(ASET[0], BSET[2], acc[(MB)+0][1], 0, 0, 0); \
    acc[(MB)+1][0] = __builtin_amdgcn_mfma_f32_32x32x16_bf16(ASET[2], BSET[0], acc[(MB)+1][0], 0, 0, 0); \
    acc[(MB)+1][1] = __builtin_amdgcn_mfma_f32_32x32x16_bf16(ASET[2], BSET[2], acc[(MB)+1][1], 0, 0, 0); \
    acc[(MB)+0][0] = __builtin_amdgcn_mfma_f32_32x32x16_bf16(ASET[1], BSET[1], acc[(MB)+0][0], 0, 0, 0); \
    acc[(MB)+0][1] = __builtin_amdgcn_mfma_f32_32x32x16_bf16(ASET[1], BSET[3], acc[(MB)+0][1], 0, 0, 0); \
    acc[(MB)+1][0] = __builtin_amdgcn_mfma_f32_32x32x16_bf16(ASET[3], BSET[1], acc[(MB)+1][0], 0, 0, 0); \
    acc[(MB)+1][1] = __builtin_amdgcn_mfma_f32_32x32x16_bf16(ASET[3], BSET[3], acc[(MB)+1][1], 0, 0, 0); \
    __builtin_amdgcn_s_setprio(0); } while (0)
#define DRAIN_LGKM asm volatile("s_waitcnt lgkmcnt(0)" ::: "memory")
#define WAIT_VM4   asm volatile("s_waitcnt vmcnt(4)" ::: "memory")
#define PH_BAR __builtin_amdgcn_s_barrier()

    // ---- prologue: identical to r14 ----
    STG_B(0, 0u, 0); STG_B(0, 0u, 1);
    STG_A(0, 0u, 0); STG_A(0, 0u, 1);
    STG_B(1, 65536u, 0); STG_B(1, 65536u, 1);
    STG_A(1, 65536u, 0);
    asm volatile("s_waitcnt vmcnt(6)" ::: "memory");
    PH_BAR;
    LDA4(aE, 0u, 0, csA, csB); LDB4(bE, 0u, csA, csB);   // (t0, mh0, kk0)

#pragma unroll 1
    for (int i = 0; i < NITER; ++i) {
        const int tb = 2 * i + 1;
        const int tc = (2 * i + 2 < 32) ? 2 * i + 2 : 31;  // src clamp; dest buf0
        const int td = (2 * i + 3 < 32) ? 2 * i + 3 : 31;  // src clamp; dest buf1

        // ph1: load q=(ta,mh0,kk1); MFMA q=(ta,mh0,kk0)
        LDA4(aO, 0u, 0, csC, csD); LDB4(bO, 0u, csC, csD);
        STG_A(tb, 65536u, 1);
        MF8(aE, bE, 0);
        DRAIN_LGKM; PH_BAR;
        // ph2: load q=(ta,mh1,kk0); MFMA q=(ta,mh0,kk1)
        LDA4(aE, 0u, 1, csA, csB);
        STG_B(tc, 0u, 0);
        MF8(aO, bO, 0);
        PH_BAR;
        // ph3: load q=(ta,mh1,kk1); MFMA q=(ta,mh1,kk0)
        LDA4(aO, 0u, 1, csC, csD);
        STG_B(tc, 0u, 1);
        MF8(aE, bE, 2);
        DRAIN_LGKM; WAIT_VM4; PH_BAR;          // tb fully landed for ph4 reads
        // ph4: load q=(tb,mh0,kk0); MFMA q=(ta,mh1,kk1)
        LDA4(aE, 65536u, 0, csA, csB); LDB4(bE, 65536u, csA, csB);
        STG_A(tc, 0u, 0);
        MF8(aO, bO, 2);
        PH_BAR;
        // ph5: load q=(tb,mh0,kk1); MFMA q=(tb,mh0,kk0)
        LDA4(aO, 65536u, 0, csC, csD); LDB4(bO, 65536u, csC, csD);
        STG_A(tc, 0u, 1);
        MF8(aE, bE, 0);
        DRAIN_LGKM; PH_BAR;
        // ph6: load q=(tb,mh1,kk0); MFMA q=(tb,mh0,kk1)
        LDA4(aE, 65536u, 1, csA, csB);
        STG_B(td, 65536u, 0);
        MF8(aO, bO, 0);
        PH_BAR;
        // ph7: load q=(tb,mh1,kk1); MFMA q=(tb,mh1,kk0)
        LDA4(aO, 65536u, 1, csC, csD);
        STG_B(td, 65536u, 1);
        MF8(aE, bE, 2);
        DRAIN_LGKM; WAIT_VM4; PH_BAR;          // tc fully landed for ph8 reads
        // ph8: load q=(tc,mh0,kk0) [dummy at i=15]; MFMA q=(tb,mh1,kk1)
        LDA4(aE, 0u, 0, csA, csB); LDB4(bE, 0u, csA, csB);
        STG_A(td, 65536u, 0);
        MF8(aO, bO, 2);
        PH_BAR;
    }
#undef RD16
#undef LDA4
#undef LDB4
#undef STG_A
#undef STG_B
#undef MF8
#undef DRAIN_LGKM
#undef WAIT_VM4
#undef PH_BAR

    // ---- fused epilogue: 32x32 C/D layout + gate exchange across lane^16 ----
    // frag n covers gates {2n, 2n+1}; lane bit4 = gate parity; partner lane^16
    // holds the complementary gates at the same (row, j).
    const int cc = l31 & 15;
    const int hi = (l31 >> 4) & 1;
    const int j = bn * 64 + wn * 16 + cc;
    const float b0 = Ub[j];
    const float b1 = Ub[1024 + j];
    const float b2 = Ub[2048 + j];
    const float b3 = Ub[3072 + j];
    const int row0 = bm * BM + wm * 128 + (lhi << 2);

#pragma unroll
    for (int m = 0; m < 4; ++m) {
#pragma unroll
        for (int reg = 0; reg < 16; ++reg) {
            const int row = row0 + m * 32 + (reg & 3) + ((reg >> 2) << 3);
            const float pa = acc[m][0][reg];           // gate 0 (lo) / 1 (hi)
            const float pb = acc[m][1][reg];           // gate 2 (lo) / 3 (hi)
            const float xa = __shfl_xor(pa, 16);
            const float xb = __shfl_xor(pb, 16);
            const float fpre = hi ? xa : pa;
            const float ipre = hi ? pa : xa;
            const float opre = hi ? xb : pb;
            const float gpre = hi ? pb : xb;
            const float cp = c_prev[(size_t)row * HID + j];
            const float f  = sigmoidf_(fpre + b0);
            const float it = sigmoidf_(ipre + b1);
            const float o  = sigmoidf_(opre + b2);
            const float gg = tanhf_(gpre + b3);
            const float cv = f * cp + it * gg;
            if (hi) out[(size_t)BATCH * HID + (size_t)row * HID + j] = cv;
            else    out[(size_t)row * HID + j] = o * tanhf_(cv);
        }
    }
}

// ---------------------------------------------------------------------------
extern "C" void kernel_launch(void* const* d_in, const int* in_sizes, int n_in,
                              void* d_out, int out_size, void* d_ws, size_t ws_size,
                              hipStream_t stream) {
    const float* x      = (const float*)d_in[0];
    const float* h_prev = (const float*)d_in[1];
    const float* c_prev = (const float*)d_in[2];
    const float* U_w    = (const float*)d_in[3];
    const float* U_b    = (const float*)d_in[4];
    const float* W_w    = (const float*)d_in[5];
    float* out = (float*)d_out;

    char* ws = (char*)d_ws;
    __hip_bfloat16* Acat = (__hip_bfloat16*)ws;                      // 16 MB
    __hip_bfloat16* Bcat = (__hip_bfloat16*)(ws + (16u << 20));      // 16 MB

    convert_kernel<<<8192, 256, 0, stream>>>(x, h_prev, U_w, W_w, Acat, Bcat);
    gemm_lstm_kernel<<<256, 512, 0, stream>>>(Acat, Bcat, U_b, c_prev, out);
}

// Round 16
// 82.955 us; speedup vs baseline: 1.2448x; 1.2448x over previous
//
#include <hip/hip_runtime.h>
#include <hip/hip_bf16.h>

// Problem: B=4096, IN=1024, H=1024.
// pre = x@U^T + h@W^T + Ub -> gates -> h_t, c_t   (fused after convert)
// GEMM: M=4096 (batch), N=4096 (4H permuted), K=2048 (IN+H concat)
//
// Round-16: RESTORE round-14 configuration (best measured: 82.0 us total,
// gemm 71.5 us, 961 TF, MfmaUtil ~39%, 0 bank conflicts, absmax 0.03125).
// r15's 32x32x16 experiment regressed (VGPR clamp at 128 serialized the
// f32x16 accumulator ping-pong); the 16x16x32 8-phase E/O schedule is the
// optimum across all 9 structural axes tested this session.
//
// Schedule (8 phases / 2 K-tiles per iter, BK=64, 2 LDS buffers 128 KB):
//   each phase: {ds_read quad for NEXT phase (E/O reg ping-pong) || stage
//   1 half-tile} -> setprio(1) 16 MFMA setprio(0) -> [lgkm drain at odd
//   phases; vmcnt(4) at ph3/ph7] -> s_barrier.
// Write-safety: odd-phase lgkmcnt(0) drains ensure a region's in-flight
// ds_reads complete >=1 barrier before its restage. vmcnt(4) at ph3/ph7
// retires the full next K-tile (16 stage-loads/iter/thread; 4 newest left
// in flight) before its reads; barrier makes it cross-wave visible.

#define BATCH 4096
#define HID   1024
#define KDIM  2048

#define BM 256
#define BN 256
#define BK 64
#define NITER (KDIM / (2 * BK))   // 16

typedef __bf16 bf16x8 __attribute__((ext_vector_type(8)));
typedef float  f32x4  __attribute__((ext_vector_type(4)));

__device__ __forceinline__ void async_load16(const void* g, void* l) {
    __builtin_amdgcn_global_load_lds(
        (const __attribute__((address_space(1))) void*)g,
        (__attribute__((address_space(3))) void*)l,
        16, 0, 0);
}

__device__ __forceinline__ float sigmoidf_(float v) {
    return 1.0f / (1.0f + __expf(-v));
}
__device__ __forceinline__ float tanhf_(float v) {
    return 1.0f - 2.0f / (__expf(2.0f * v) + 1.0f);
}

// ---------------------------------------------------------------------------
// Kernel 1: f32 -> bf16 conversion + K-concat; B side gate-permuted.
// ---------------------------------------------------------------------------
__global__ __launch_bounds__(256) void convert_kernel(
    const float* __restrict__ x, const float* __restrict__ h,
    const float* __restrict__ U, const float* __restrict__ W,
    __hip_bfloat16* __restrict__ Acat, __hip_bfloat16* __restrict__ Bcat)
{
    const int CH_PER_MAT = (4096 * KDIM) / 8;
    int idx = blockIdx.x * blockDim.x + threadIdx.x;
    bool isB = idx >= CH_PER_MAT;
    int c = isB ? (idx - CH_PER_MAT) : idx;
    int row  = c >> 8;
    int col  = (c & 255) << 3;
    int srow = row;
    if (isB) {
        int g  = (row >> 4) & 3;
        int j  = ((row >> 8) << 6) + (((row >> 6) & 3) << 4) + (row & 15);
        srow = g * 1024 + j;
    }
    const float* src;
    if (col < 1024) src = (isB ? U : x) + (size_t)srow * 1024 + col;
    else            src = (isB ? W : h) + (size_t)srow * 1024 + (col - 1024);
    float4 v0 = *(const float4*)(src);
    float4 v1 = *(const float4*)(src + 4);
    __hip_bfloat16 tmp[8];
    tmp[0] = __float2bfloat16(v0.x); tmp[1] = __float2bfloat16(v0.y);
    tmp[2] = __float2bfloat16(v0.z); tmp[3] = __float2bfloat16(v0.w);
    tmp[4] = __float2bfloat16(v1.x); tmp[5] = __float2bfloat16(v1.y);
    tmp[6] = __float2bfloat16(v1.z); tmp[7] = __float2bfloat16(v1.w);
    __hip_bfloat16* dst = (isB ? Bcat : Acat) + (size_t)row * KDIM + col;
    *(bf16x8*)dst = *(const bf16x8*)tmp;
}

// ---------------------------------------------------------------------------
// Kernel 2: fused bf16 GEMM + LSTM gates, 8-phase schedule (r14 config).
// ---------------------------------------------------------------------------
__global__ __launch_bounds__(512, 1) void gemm_lstm_kernel(
    const __hip_bfloat16* __restrict__ A,   // [4096][2048]
    const __hip_bfloat16* __restrict__ Bm,  // [4096][2048] gate-permuted
    const float* __restrict__ Ub,           // [4096]
    const float* __restrict__ c_prev,       // [4096][1024]
    float* __restrict__ out)                // h_t ++ c_t
{
    __shared__ __align__(16) unsigned char smem[131072];  // 2 bufs x 64 KB

    const int tid  = threadIdx.x;
    const int lane = tid & 63;
    const int wid  = tid >> 6;
    const int wm   = wid >> 2;     // 0..1
    const int wn   = wid & 3;      // 0..3

    // L2-locality map (r7): each XCD owns a 4x8 rectangle of the 16x16 grid.
    int wg  = blockIdx.x;
    const int xcd = wg & 7;
    const int i_  = wg >> 3;
    const int bm = ((xcd >> 1) << 2) + (i_ >> 3);
    const int bn = ((xcd & 1) << 3) + (i_ & 7);

    const __hip_bfloat16* Ab = A  + (size_t)bm * BM * KDIM;
    const __hip_bfloat16* Bb = Bm + (size_t)bn * BN * KDIM;

    // ds_read addressing: half-tile [128 rows][64 cols] bf16, 8 x 16B slots/row.
    // swizzle: phys_slot = logical_slot ^ ((row>>1)&7).
    const int frow = lane & 15;
    const int kq   = lane >> 4;                       // 0..3
    const int esw  = (frow >> 1) & 7;
    const unsigned xs0 = (unsigned)((kq ^ esw) << 4); // kk=0 slot byte
    const unsigned xs1 = xs0 ^ 64u;                   // kk=1
    const unsigned wmBase = (unsigned)wm * 16384u;    // A-half = wm
    const unsigned bnBase = (unsigned)(wn >> 1) * 16384u;
    const unsigned bnRow  = (unsigned)(wn & 1) * 64u;

    // staging: 1024 chunks/half-tile; thread stages ch0=tid, ch1=512+tid.
    // linear LDS dest; global source pre-swizzled (both-sides rule).
    const int ch0 = tid,           ch1 = 512 + tid;
    const int sr0 = ch0 >> 3,      sr1 = ch1 >> 3;
    const int sc0 = ((ch0 & 7) ^ ((sr0 >> 1) & 7)) << 3;
    const int sc1 = ((ch1 & 7) ^ ((sr1 >> 1) & 7)) << 3;
    const size_t ga0 = (size_t)sr0 * KDIM + sc0;
    const size_t ga1 = (size_t)sr1 * KDIM + sc1;

    f32x4 acc[8][4] = {};
    bf16x8 arE[4], arO[4], brE[4], brO[4];

#define RD16(B) (*(const bf16x8*)(smem + (B)))
#define LDA4(SET, BUFB, MH, XS) do { \
    const unsigned _b = (BUFB) + wmBase; \
    SET[0] = RD16(_b + (unsigned)((MH)*64 +  0 + frow)*128u + (XS)); \
    SET[1] = RD16(_b + (unsigned)((MH)*64 + 16 + frow)*128u + (XS)); \
    SET[2] = RD16(_b + (unsigned)((MH)*64 + 32 + frow)*128u + (XS)); \
    SET[3] = RD16(_b + (unsigned)((MH)*64 + 48 + frow)*128u + (XS)); } while (0)
#define LDB4(SET, BUFB, XS) do { \
    const unsigned _b = (BUFB) + 32768u + bnBase; \
    SET[0] = RD16(_b + (bnRow +  0 + frow)*128u + (XS)); \
    SET[1] = RD16(_b + (bnRow + 16 + frow)*128u + (XS)); \
    SET[2] = RD16(_b + (bnRow + 32 + frow)*128u + (XS)); \
    SET[3] = RD16(_b + (bnRow + 48 + frow)*128u + (XS)); } while (0)
#define STG_A(TSRC, BUFB, H) do { \
    const unsigned _rg = (BUFB) + (H)*16384u; \
    const __hip_bfloat16* _s = Ab + (size_t)(H)*128*KDIM + (size_t)(TSRC)*64; \
    async_load16(_s + ga0, smem + _rg + (unsigned)ch0*16u); \
    async_load16(_s + ga1, smem + _rg + (unsigned)ch1*16u); } while (0)
#define STG_B(TSRC, BUFB, H) do { \
    const unsigned _rg = (BUFB) + 32768u + (H)*16384u; \
    const __hip_bfloat16* _s = Bb + (size_t)(H)*128*KDIM + (size_t)(TSRC)*64; \
    async_load16(_s + ga0, smem + _rg + (unsigned)ch0*16u); \
    async_load16(_s + ga1, smem + _rg + (unsigned)ch1*16u); } while (0)
#define MF16(ASET, BSET, MB) do { \
    __builtin_amdgcn_s_setprio(1); \
    _Pragma("unroll") for (int _m = 0; _m < 4; ++_m) \
    _Pragma("unroll") for (int _n = 0; _n < 4; ++_n) \
        acc[(MB)+_m][_n] = __builtin_amdgcn_mfma_f32_16x16x32_bf16( \
            ASET[_m], BSET[_n], acc[(MB)+_m][_n], 0, 0, 0); \
    __builtin_amdgcn_s_setprio(0); } while (0)
#define DRAIN_LGKM asm volatile("s_waitcnt lgkmcnt(0)" ::: "memory")
#define WAIT_VM4   asm volatile("s_waitcnt vmcnt(4)" ::: "memory")
#define PH_BAR __builtin_amdgcn_s_barrier()

    // ---- prologue: stage K0 (4 halves) + B1 (2) + A1h0; wait K0; read quad0 ----
    STG_B(0, 0u, 0); STG_B(0, 0u, 1);
    STG_A(0, 0u, 0); STG_A(0, 0u, 1);
    STG_B(1, 65536u, 0); STG_B(1, 65536u, 1);
    STG_A(1, 65536u, 0);
    asm volatile("s_waitcnt vmcnt(6)" ::: "memory");
    PH_BAR;
    LDA4(arE, 0u, 0, xs0); LDB4(brE, 0u, xs0);   // quad 0: (t0, mh0, kk0)

#pragma unroll 1
    for (int i = 0; i < NITER; ++i) {
        const int tb = 2 * i + 1;
        const int tc = (2 * i + 2 < 32) ? 2 * i + 2 : 31;  // src clamp; dest buf0
        const int td = (2 * i + 3 < 32) ? 2 * i + 3 : 31;  // src clamp; dest buf1

        // ph1: load q=(ta,mh0,kk1); MFMA q=(ta,mh0,kk0)
        LDA4(arO, 0u, 0, xs1); LDB4(brO, 0u, xs1);
        STG_A(tb, 65536u, 1);
        MF16(arE, brE, 0);
        DRAIN_LGKM; PH_BAR;
        // ph2: load q=(ta,mh1,kk0); MFMA q=(ta,mh0,kk1)
        LDA4(arE, 0u, 1, xs0);
        STG_B(tc, 0u, 0);
        MF16(arO, brO, 0);
        PH_BAR;
        // ph3: load q=(ta,mh1,kk1); MFMA q=(ta,mh1,kk0)
        LDA4(arO, 0u, 1, xs1);
        STG_B(tc, 0u, 1);
        MF16(arE, brE, 4);
        DRAIN_LGKM; WAIT_VM4; PH_BAR;          // tb fully landed for ph4 reads
        // ph4: load q=(tb,mh0,kk0); MFMA q=(ta,mh1,kk1)
        LDA4(arE, 65536u, 0, xs0); LDB4(brE, 65536u, xs0);
        STG_A(tc, 0u, 0);
        MF16(arO, brO, 4);
        PH_BAR;
        // ph5: load q=(tb,mh0,kk1); MFMA q=(tb,mh0,kk0)
        LDA4(arO, 65536u, 0, xs1); LDB4(brO, 65536u, xs1);
        STG_A(tc, 0u, 1);
        MF16(arE, brE, 0);
        DRAIN_LGKM; PH_BAR;
        // ph6: load q=(tb,mh1,kk0); MFMA q=(tb,mh0,kk1)
        LDA4(arE, 65536u, 1, xs0);
        STG_B(td, 65536u, 0);
        MF16(arO, brO, 0);
        PH_BAR;
        // ph7: load q=(tb,mh1,kk1); MFMA q=(tb,mh1,kk0)
        LDA4(arO, 65536u, 1, xs1);
        STG_B(td, 65536u, 1);
        MF16(arE, brE, 4);
        DRAIN_LGKM; WAIT_VM4; PH_BAR;          // tc fully landed for ph8 reads
        // ph8: load q=(tc,mh0,kk0) [dummy at i=15]; MFMA q=(tb,mh1,kk1)
        LDA4(arE, 0u, 0, xs0); LDB4(brE, 0u, xs0);
        STG_A(td, 65536u, 0);
        MF16(arO, brO, 4);
        PH_BAR;
    }
#undef RD16
#undef LDA4
#undef LDB4
#undef STG_A
#undef STG_B
#undef MF16
#undef DRAIN_LGKM
#undef WAIT_VM4
#undef PH_BAR

    // ---- fused epilogue: gates lane-local thanks to B permutation ----
    const int j = bn * 64 + wn * 16 + (lane & 15);
    const float bf_ = Ub[j];
    const float bi_ = Ub[1024 + j];
    const float bo_ = Ub[2048 + j];
    const float bg_ = Ub[3072 + j];
    const int row0 = bm * BM + wm * 128 + ((lane >> 4) << 2);

    float cp[8][4];
#pragma unroll
    for (int m = 0; m < 8; ++m)
#pragma unroll
        for (int r = 0; r < 4; ++r)
            cp[m][r] = c_prev[(size_t)(row0 + m * 16 + r) * HID + j];

#pragma unroll
    for (int m = 0; m < 8; ++m) {
#pragma unroll
        for (int r = 0; r < 4; ++r) {
            const int row = row0 + m * 16 + r;
            const float f  = sigmoidf_(acc[m][0][r] + bf_);
            const float it = sigmoidf_(acc[m][1][r] + bi_);
            const float o  = sigmoidf_(acc[m][2][r] + bo_);
            const float gg = tanhf_(acc[m][3][r] + bg_);
            const float cv = f * cp[m][r] + it * gg;
            const float hv = o * tanhf_(cv);
            out[(size_t)row * HID + j] = hv;
            out[(size_t)BATCH * HID + (size_t)row * HID + j] = cv;
        }
    }
}

// ---------------------------------------------------------------------------
extern "C" void kernel_launch(void* const* d_in, const int* in_sizes, int n_in,
                              void* d_out, int out_size, void* d_ws, size_t ws_size,
                              hipStream_t stream) {
    const float* x      = (const float*)d_in[0];
    const float* h_prev = (const float*)d_in[1];
    const float* c_prev = (const float*)d_in[2];
    const float* U_w    = (const float*)d_in[3];
    const float* U_b    = (const float*)d_in[4];
    const float* W_w    = (const float*)d_in[5];
    float* out = (float*)d_out;

    char* ws = (char*)d_ws;
    __hip_bfloat16* Acat = (__hip_bfloat16*)ws;                      // 16 MB
    __hip_bfloat16* Bcat = (__hip_bfloat16*)(ws + (16u << 20));      // 16 MB

    convert_kernel<<<8192, 256, 0, stream>>>(x, h_prev, U_w, W_w, Acat, Bcat);
    gemm_lstm_kernel<<<256, 512, 0, stream>>>(Acat, Bcat, U_b, c_prev, out);
}